// Round 15
// baseline (648.743 us; speedup 1.0000x reference)
//
#include <hip/hip_runtime.h>
#include <hip/hip_bf16.h>
#include <stdint.h>

#define NN 8192
#define DIN 512
#define DOUT 256
#define NSPLIT 4
#define STRIP (NN / NSPLIT) /* 2048 */

typedef short short8 __attribute__((ext_vector_type(8)));
typedef float floatx4 __attribute__((ext_vector_type(4)));

__device__ __forceinline__ unsigned short f2bf_rne(float x) {
  unsigned u = __float_as_uint(x);
  u += 0x7fffu + ((u >> 16) & 1u);
  return (unsigned short)(u >> 16);
}
__device__ __forceinline__ float bf2f(unsigned short h) {
  return __uint_as_float(((unsigned)h) << 16);
}

// -------- weight transpose+cvt: W fp32 [512][256] -> WT bf16 [256][512] --------
__global__ __launch_bounds__(256) void kt_transpose(const float* __restrict__ Wg,
                                                    unsigned short* __restrict__ WT) {
  __shared__ unsigned short sm[32][33];
  int tid = threadIdx.x;
  int bk = blockIdx.x >> 3;  // k tile
  int bn = blockIdx.x & 7;   // n tile
  int k0 = bk * 32, n0 = bn * 32;
  int r = tid >> 3, c4 = (tid & 7) * 4;
  const float* src = Wg + (size_t)(k0 + r) * DOUT + n0 + c4;
#pragma unroll
  for (int x = 0; x < 4; ++x) sm[r][c4 + x] = f2bf_rne(src[x]);
  __syncthreads();
  unsigned short* dst = WT + (size_t)(n0 + r) * DIN + k0 + c4;
#pragma unroll
  for (int x = 0; x < 4; ++x) dst[x] = sm[c4 + x][r];
}

// -- GEMM1 (MFMA): WhT[d][i] = sum_k X[i][k] W[k][d]; unchanged from R14 pass --
__global__ __launch_bounds__(256) void kt_gemm1(const float* __restrict__ X,
                                                const unsigned short* __restrict__ WT,
                                                const float* __restrict__ Ab,
                                                unsigned short* __restrict__ WhT,
                                                float* __restrict__ Wh1,
                                                float* __restrict__ Wh2) {
  int tid = threadIdx.x;
  int w = tid >> 6, lane = tid & 63;
  int col = lane & 15, q = lane >> 4;
  int db = blockIdx.x & 3;   // d block (64 each)
  int ib = blockIdx.x >> 2;  // i block (64 each), 128 of them
  int i0 = ib * 64;
  int drow = db * 64 + w * 16 + col;  // A row (d), m = lane&15
  const unsigned short* abase = WT + (size_t)drow * DIN + q * 8;
  const float* xbase = X + (size_t)(i0 + col) * DIN + q * 8;
  floatx4 acc[4];
#pragma unroll
  for (int t = 0; t < 4; ++t) acc[t] = (floatx4)(0.0f);
  for (int k0 = 0; k0 < DIN; k0 += 32) {
    short8 af = *(const short8*)(abase + k0);
#pragma unroll
    for (int t = 0; t < 4; ++t) {
      const float* xp = xbase + (size_t)t * 16 * DIN + k0;
      float4 xa = *(const float4*)xp;
      float4 xb = *(const float4*)(xp + 4);
      short8 bf;
      bf[0] = (short)f2bf_rne(xa.x); bf[1] = (short)f2bf_rne(xa.y);
      bf[2] = (short)f2bf_rne(xa.z); bf[3] = (short)f2bf_rne(xa.w);
      bf[4] = (short)f2bf_rne(xb.x); bf[5] = (short)f2bf_rne(xb.y);
      bf[6] = (short)f2bf_rne(xb.z); bf[7] = (short)f2bf_rne(xb.w);
      acc[t] = __builtin_amdgcn_mfma_f32_16x16x32_bf16(af, bf, acc[t], 0, 0, 0);
    }
  }
  // D: col=lane&15 -> i; row=q*4+r -> d
  int dq = db * 64 + w * 16 + q * 4;
  float a1v[4], a2v[4];
#pragma unroll
  for (int r = 0; r < 4; ++r) { a1v[r] = Ab[dq + r]; a2v[r] = Ab[DOUT + dq + r]; }
#pragma unroll
  for (int t = 0; t < 4; ++t) {
    floatx4 v = acc[t];
    int icol = i0 + t * 16 + col;
#pragma unroll
    for (int r = 0; r < 4; ++r) WhT[(size_t)(dq + r) * NN + icol] = f2bf_rne(v[r]);
    float p1 = v[0] * a1v[0] + v[1] * a1v[1] + v[2] * a1v[2] + v[3] * a1v[3];
    float p2 = v[0] * a2v[0] + v[1] * a2v[1] + v[2] * a2v[2] + v[3] * a2v[3];
    p1 += __shfl_xor(p1, 16);
    p1 += __shfl_xor(p1, 32);
    p2 += __shfl_xor(p2, 16);
    p2 += __shfl_xor(p2, 32);
    if (q == 0) {
      atomicAdd(&Wh1[icol], p1);
      atomicAdd(&Wh2[icol], p2);
    }
  }
}

// ------- barrier-free fused attention: no LDS, no atomics, no __syncthreads -------
// Each wave owns 16 i-rows x full d(256) for one j-strip. B-fragments are read
// directly from WhT in global (L2-resident 4MB; 4x block redundancy absorbed by
// L1's 16KB step footprint). fp32 partials go to pbuf[s]; merged by kt_merge.
__device__ __forceinline__ short8 build_a(int4 pa, int4 pb, float wh1, const float* w2,
                                          float& lsum) {
  int av[8] = {pa.x, pa.y, pa.z, pa.w, pb.x, pb.y, pb.z, pb.w};
  short8 af;
#pragma unroll
  for (int e = 0; e < 8; ++e) {
    float sc = wh1 + w2[e];
    sc = fmaxf(sc, 0.2f * sc);  // LeakyReLU
    float ex = __expf(sc);
    float wv = (av[e] != 0) ? ex : 0.0f;
    unsigned short hb = f2bf_rne(wv);
    af[e] = (short)hb;
    lsum += bf2f(hb);  // denominator from the *rounded* weight
  }
  return af;
}

// NOTE: single-arg launch_bounds only (the 2-arg form correlated with the
// R11-13 container-failure streak; never again).
__global__ __launch_bounds__(256) void kt_attn(const int* __restrict__ adj,
                                               const unsigned short* __restrict__ WhT,
                                               const float* __restrict__ Wh1,
                                               const float* __restrict__ Wh2,
                                               float* __restrict__ pbuf,
                                               float* __restrict__ lbuf) {
  int tid = threadIdx.x;
  int w = tid >> 6, lane = tid & 63;
  int col = lane & 15, q = lane >> 4;
  int s = blockIdx.x & (NSPLIT - 1);
  int ib = blockIdx.x / NSPLIT;
  int i0 = ib * 64;
  int jb = s * STRIP;
  int arow = i0 + w * 16 + col;  // this lane's A-fragment row

  float wh1v = Wh1[arow];
  const int* aptr = adj + ((size_t)arow << 13) + jb + q * 8;
  const float* w2p = Wh2 + jb + q * 8;
  const unsigned short* bbase = WhT + (size_t)col * NN + jb + q * 8;

  floatx4 acc[16];
#pragma unroll
  for (int t = 0; t < 16; ++t) acc[t] = (floatx4)(0.0f);
  float lp = 0.f;

  // adj register prefetch, 2 steps deep (slot = step parity)
  int4 ada[2], adb[2];
#pragma unroll
  for (int p = 0; p < 2; ++p) {
    ada[p] = *(const int4*)(aptr + p * 32);
    adb[p] = *(const int4*)(aptr + p * 32 + 4);
  }

  const int NSTEP = STRIP / 32;  // 64
#pragma unroll 1
  for (int k = 0; k < NSTEP; ++k) {
    int jl = k * 32;
    floatx4 w2a = *(const floatx4*)(w2p + jl);
    floatx4 w2b = *(const floatx4*)(w2p + jl + 4);
    float w2[8] = {w2a[0], w2a[1], w2a[2], w2a[3], w2b[0], w2b[1], w2b[2], w2b[3]};
    int p = k & 1;
    short8 af = build_a(ada[p], adb[p], wh1v, w2, lp);
    if (k + 2 < NSTEP) {  // refill the freed slot with step k+2's adj
      ada[p] = *(const int4*)(aptr + jl + 64);
      adb[p] = *(const int4*)(aptr + jl + 68);
    }
    // B-fragments straight from global (L1/L2); two halves of 8 to bound regs
#pragma unroll
    for (int h = 0; h < 2; ++h) {
      short8 bf[8];
#pragma unroll
      for (int t = 0; t < 8; ++t)
        bf[t] = *(const short8*)(bbase + (size_t)((h * 8 + t) * 16) * NN + jl);
#pragma unroll
      for (int t = 0; t < 8; ++t)
        acc[h * 8 + t] = __builtin_amdgcn_mfma_f32_16x16x32_bf16(af, bf[t], acc[h * 8 + t], 0, 0, 0);
    }
  }

  // l: sum over q-chunks (lanes m, m+16, m+32, m+48) -> row sums in lanes 0..15
  lp += __shfl_xor(lp, 16);
  lp += __shfl_xor(lp, 32);
  if (lane < 16) lbuf[(size_t)s * NN + i0 + w * 16 + lane] = lp;

  // fp32 partial write (plain streaming stores; rows via D-layout q*4+r)
  float* pb = pbuf + (size_t)s * NN * DOUT + (size_t)(i0 + w * 16 + q * 4) * DOUT + col;
#pragma unroll
  for (int t = 0; t < 16; ++t) {
    floatx4 v = acc[t];
#pragma unroll
    for (int r = 0; r < 4; ++r) pb[(size_t)r * DOUT + t * 16] = v[r];
  }
}

// ---------------- merge partials + normalize + ELU -> fp32 out ----------------
__global__ __launch_bounds__(256) void kt_merge(const float* __restrict__ pbuf,
                                                const float* __restrict__ lbuf,
                                                float* __restrict__ out) {
  int i = blockIdx.x;
  int d = threadIdx.x;
  size_t idx = (size_t)i * DOUT + d;
  float a = 0.f, l = 0.f;
#pragma unroll
  for (int s = 0; s < NSPLIT; ++s) {
    a += pbuf[(size_t)s * NN * DOUT + idx];
    l += lbuf[(size_t)s * NN + i];
  }
  float x = a / l;
  x = x > 0.f ? x : (__expf(x) - 1.f);
  out[idx] = x;
}

extern "C" void kernel_launch(void* const* d_in, const int* in_sizes, int n_in,
                              void* d_out, int out_size, void* d_ws, size_t ws_size,
                              hipStream_t stream) {
  const float* X = (const float*)d_in[0];       // input fp32 [8192][512]
  const int* adj = (const int*)d_in[1];         // int32 [8192][8192]
  const float* Wg = (const float*)d_in[2];      // weight fp32 [512][256]
  const float* Ab = (const float*)d_in[3];      // a fp32 [512]
  float* out = (float*)d_out;                   // fp32 [8192][256]

  // workspace: pbuf(32MB) | lbuf(128KB) | Wh1 | Wh2 | WT | WhT  (~36.5 MB;
  // ws_size >= 38.5 MB proven by R1/R2 executing with that footprint)
  char* ws = (char*)d_ws;
  float* pbuf = (float*)ws;                                  // 32 MB (fully written)
  size_t off = (size_t)NSPLIT * NN * DOUT * 4;
  float* lbuf = (float*)(ws + off); off += (size_t)NSPLIT * NN * 4;  // fully written
  float* Wh1 = (float*)(ws + off);  off += (size_t)NN * 4;
  float* Wh2 = (float*)(ws + off);  off += (size_t)NN * 4;
  unsigned short* WT = (unsigned short*)(ws + off);
  off += (size_t)DOUT * DIN * 2;                             // 256 KB
  unsigned short* WhT = (unsigned short*)(ws + off);
  off += (size_t)DOUT * NN * 2;                              // 4 MB

  hipMemsetAsync(Wh1, 0, 2 * (size_t)NN * 4, stream);  // zero Wh1+Wh2 only (64 KB)
  kt_transpose<<<128, 256, 0, stream>>>(Wg, WT);
  kt_gemm1<<<(NN / 64) * 4, 256, 0, stream>>>(X, WT, Ab, WhT, Wh1, Wh2);
  kt_attn<<<(NN / 64) * NSPLIT, 256, 0, stream>>>(adj, WhT, Wh1, Wh2, pbuf, lbuf);
  kt_merge<<<NN, 256, 0, stream>>>(pbuf, lbuf, out);
}